// Round 7
// baseline (251.068 us; speedup 1.0000x reference)
//
#include <hip/hip_runtime.h>

#define BB 2
#define LL 1536
#define DD 1024
#define HH 16
#define HDD 64
#define PP 1024
#define PBS 1544  // p_b row stride in shorts: 16B-aligned

typedef __attribute__((ext_vector_type(8))) __bf16 bf16x8;
typedef __attribute__((ext_vector_type(4))) float f32x4;
typedef __attribute__((ext_vector_type(2))) float f32x2;

__device__ __forceinline__ float b2f(unsigned short u) {
  unsigned int x = ((unsigned int)u) << 16;
  return __builtin_bit_cast(float, x);
}
__device__ __forceinline__ unsigned short f2b(float f) {
  unsigned int x = __builtin_bit_cast(unsigned int, f);
  unsigned int r = (x + 0x7FFFu + ((x >> 16) & 1u)) >> 16;
  return (unsigned short)r;
}
__device__ __forceinline__ bf16x8 ldb8(const unsigned short* p) {
  return __builtin_bit_cast(bf16x8, *(const uint4*)p);
}
__device__ __forceinline__ f32x2 mk2(float a, float b) {
  f32x2 r;
  r.x = a;
  r.y = b;
  return r;
}
// async global->LDS, 16B per lane; lds dst = wave-uniform base + lane*16
__device__ __forceinline__ void gl_lds16(const unsigned short* g,
                                         unsigned short* l) {
  __builtin_amdgcn_global_load_lds(
      (const __attribute__((address_space(1))) void*)g,
      (__attribute__((address_space(3))) void*)l, 16, 0, 0);
}

// ---------------- prep: cast hs to bf16 ----------------
__global__ __launch_bounds__(256) void cast_hs(const float* __restrict__ src,
                                               unsigned short* __restrict__ dst) {
  const int idx = (blockIdx.x * 256 + threadIdx.x) * 8;
  float4 a = *(const float4*)(src + idx);
  float4 b = *(const float4*)(src + idx + 4);
  uint4 u;
  u.x = (unsigned int)f2b(a.x) | ((unsigned int)f2b(a.y) << 16);
  u.y = (unsigned int)f2b(a.z) | ((unsigned int)f2b(a.w) << 16);
  u.z = (unsigned int)f2b(b.x) | ((unsigned int)f2b(b.y) << 16);
  u.w = (unsigned int)f2b(b.z) | ((unsigned int)f2b(b.w) << 16);
  *(uint4*)(dst + idx) = u;
}

// ---------------- prep: cast+transpose W[k][n] fp32 -> WT[n][k] bf16 --------
__global__ __launch_bounds__(256) void transpose_w(
    const float* __restrict__ Wq, const float* __restrict__ Wk,
    const float* __restrict__ Wv, const float* __restrict__ Wo,
    unsigned short* __restrict__ WT) {
  __shared__ float tile[64][68];
  const float* W = (blockIdx.z == 0) ? Wq
                   : (blockIdx.z == 1) ? Wk
                   : (blockIdx.z == 2) ? Wv : Wo;
  unsigned short* O = WT + (size_t)blockIdx.z * 1024 * 1024;
  const int t = threadIdx.x;
  const int r0 = blockIdx.y * 64;  // k rows
  const int c0 = blockIdx.x * 64;  // n cols
#pragma unroll
  for (int i = 0; i < 4; ++i) {
    const int row = (t >> 4) + i * 16;
    const int col = (t & 15) * 4;
    *(float4*)&tile[row][col] = *(const float4*)&W[(size_t)(r0 + row) * 1024 + c0 + col];
  }
  __syncthreads();
#pragma unroll
  for (int i = 0; i < 4; ++i) {
    const int n = (t >> 4) + i * 16;
    const int k4 = (t & 15) * 4;
    uint2 u;
    u.x = (unsigned int)f2b(tile[k4 + 0][n]) |
          ((unsigned int)f2b(tile[k4 + 1][n]) << 16);
    u.y = (unsigned int)f2b(tile[k4 + 2][n]) |
          ((unsigned int)f2b(tile[k4 + 3][n]) << 16);
    *(uint2*)&O[(size_t)(c0 + n) * 1024 + r0 + k4] = u;
  }
}

// ---------------- bf16 MFMA GEMM: C[M,1024] = A[M,1024] @ Bt[1024,1024]^T ----
// R7: 64x128 tile (was 128x128) -> 2x blocks for occupancy/imbalance; BK=32,
// 4 waves, each 32x64 (2x4 MFMA). LDS 12 KB.
// MODE 0: bf16 *0.125 row-major (Q). MODE 1: K fragment-linear
// KF[(bh*96+kt)*2+f][lane][8]. MODE 2: V fragment-linear
// VF[(bh*4+hg)*48+tile][lane][8]. MODE 3: fp32 row-major.
template <int MODE>
__device__ __forceinline__ void gemm_mfma_body(
    const unsigned short* __restrict__ A, const unsigned short* __restrict__ Bt,
    const float* __restrict__ bias, void* __restrict__ Cout) {
  __shared__ unsigned short As[64 * 32];   // 4 KB
  __shared__ unsigned short Bs[128 * 32];  // 8 KB
  const int t = threadIdx.x;
  const int lane = t & 63;
  const int w = t >> 6;
  const int quad = lane >> 4;
  const int lc = lane & 15;
  const int m0 = blockIdx.y * 64, n0 = blockIdx.x * 128;

  const int sr = lane >> 2;        // row within 16-row group
  const int sk = (lane & 3) * 8;   // k element offset
  const unsigned short* gA = A + (size_t)(m0 + w * 16 + sr) * 1024 + sk;
  const unsigned short* gB0 = Bt + (size_t)(n0 + w * 32 + sr) * 1024 + sk;
  const unsigned short* gB1 = gB0 + 16 * 1024;
  unsigned short* lA = As + w * 512;
  unsigned short* lB0 = Bs + w * 1024;
  unsigned short* lB1 = Bs + w * 1024 + 512;

  const int mrow0 = (w & 1) * 32, ncol0 = (w >> 1) * 64;

  f32x4 acc[2][4];
#pragma unroll
  for (int i = 0; i < 2; ++i)
#pragma unroll
    for (int j = 0; j < 4; ++j) acc[i][j] = (f32x4){0.f, 0.f, 0.f, 0.f};

  for (int k0 = 0; k0 < 1024; k0 += 32) {
    __syncthreads();  // previous iter's ds_reads done before overwrite
    gl_lds16(gA + k0, lA);
    gl_lds16(gB0 + k0, lB0);
    gl_lds16(gB1 + k0, lB1);
    __syncthreads();  // staged data visible
    bf16x8 af[2], bfr[4];
#pragma unroll
    for (int i = 0; i < 2; ++i)
      af[i] = ldb8(&As[(mrow0 + i * 16 + lc) * 32 + quad * 8]);
#pragma unroll
    for (int j = 0; j < 4; ++j)
      bfr[j] = ldb8(&Bs[(ncol0 + j * 16 + lc) * 32 + quad * 8]);
#pragma unroll
    for (int i = 0; i < 2; ++i)
#pragma unroll
      for (int j = 0; j < 4; ++j)
        acc[i][j] =
            __builtin_amdgcn_mfma_f32_16x16x32_bf16(af[i], bfr[j], acc[i][j], 0, 0, 0);
  }

#pragma unroll
  for (int i = 0; i < 2; ++i) {
    const int row0 = m0 + mrow0 + i * 16 + quad * 4;  // rows row0..row0+3
#pragma unroll
    for (int jj = 0; jj < 4; ++jj) {
      const int col = n0 + ncol0 + jj * 16 + lc;
      const float bz = bias[col];
      float o[4];
#pragma unroll
      for (int r = 0; r < 4; ++r) o[r] = acc[i][jj][r] + bz;
      if constexpr (MODE == 0) {
#pragma unroll
        for (int r = 0; r < 4; ++r)
          ((unsigned short*)Cout)[(size_t)(row0 + r) * 1024 + col] =
              f2b(o[r] * 0.125f);
      } else if constexpr (MODE == 1) {
        // K fragment-linear: key=row, tile=key/16, m=key%16, col-> f,qk,j
        const int bb = row0 / LL;
        const int kl = row0 - bb * LL;  // key local, %16 == quad*4
        const int ktl = kl >> 4;
        const int m = kl & 15;
        const int hh = col >> 6;
        const int hd = col & 63;
        const int f = hd >> 5;
        const int qk = (hd >> 3) & 3;
        const int j = hd & 7;
        unsigned short* KF = (unsigned short*)Cout;
        const size_t base =
            (((size_t)(bb * HH + hh) * 96 + ktl) * 2 + f) * 512 +
            (qk * 16 + m) * 8 + j;
#pragma unroll
        for (int r = 0; r < 4; ++r) KF[base + r * 8] = f2b(o[r]);
      } else if constexpr (MODE == 2) {
        // V fragment-linear: r=0..3 -> 4 consecutive j -> one uint2 store
        const int bb = row0 / LL;
        const int kl = row0 - bb * LL;  // key local of r=0
        const int hh = col >> 6;
        const int hd = col & 63;
        const int hg = hd >> 4;
        const int lcv = hd & 15;
        const int tile = (kl >> 5);        // gg*2 + c
        const int qv = (kl >> 3) & 3;
        const int j0 = kl & 7;             // 0 or 4
        unsigned short* VF = (unsigned short*)Cout;
        const size_t base =
            (((size_t)(bb * HH + hh) * 4 + hg) * 48 + tile) * 512 +
            (qv * 16 + lcv) * 8 + j0;
        uint2 u;
        u.x = (unsigned int)f2b(o[0]) | ((unsigned int)f2b(o[1]) << 16);
        u.y = (unsigned int)f2b(o[2]) | ((unsigned int)f2b(o[3]) << 16);
        *(uint2*)&VF[base] = u;
      } else {
#pragma unroll
        for (int r = 0; r < 4; ++r)
          ((float*)Cout)[(size_t)(row0 + r) * 1024 + col] = o[r];
      }
    }
  }
}

__global__ __launch_bounds__(256) void qkv_gemm(
    const unsigned short* __restrict__ hsb, const unsigned short* __restrict__ WT,
    const float* __restrict__ bq, const float* __restrict__ bk,
    const float* __restrict__ bv, unsigned short* __restrict__ Qb,
    unsigned short* __restrict__ KF, unsigned short* __restrict__ VF) {
  if (blockIdx.z == 0) {
    gemm_mfma_body<0>(hsb, WT, bq, Qb);
  } else if (blockIdx.z == 1) {
    gemm_mfma_body<1>(hsb, WT + 1024 * 1024, bk, KF);
  } else {
    gemm_mfma_body<2>(hsb, WT + 2 * 1024 * 1024, bv, VF);
  }
}

__global__ __launch_bounds__(256) void out_gemm(
    const unsigned short* __restrict__ ctxb,
    const unsigned short* __restrict__ WoT, const float* __restrict__ bo,
    float* __restrict__ out) {
  gemm_mfma_body<3>(ctxb, WoT, bo, out);
}

// ---------------- fused attention: scores -> softmax -> 3x diffusion -> PV ----
// One block per (b, h, 16-row q tile), 512 threads / 8 waves.
// R7: phase-3 diffusion in f32x2 packed math (v_pk_fma_f32) -> ~half the
// VALU issue of the dominant phase.
__global__ __launch_bounds__(512, 4) void attn_kernel(
    const unsigned short* __restrict__ Qb, const unsigned short* __restrict__ KF,
    const unsigned short* __restrict__ VF, const int* __restrict__ mask,
    const float* __restrict__ kernel_w, unsigned short* __restrict__ ctxb) {
  __shared__ __align__(16) unsigned short p_b[16][PBS];  // ~48.2 KB
  __shared__ unsigned int kvb[50];                       // packed key-valid bits
  __shared__ float red_s[8][16];

  const int t = threadIdx.x;
  const int lane = t & 63;
  const int w = t >> 6;        // wave id 0..7
  const int quad = lane >> 4;  // 0..3
  const int lc = lane & 15;
  const int b = blockIdx.z, h = blockIdx.y;
  const int q0 = blockIdx.x * 16;

  // key-valid bitmask via per-wave ballot (keys r*512 + w*64 + lane)
  if (t < 2) kvb[48 + t] = 0;
#pragma unroll
  for (int r = 0; r < 3; ++r) {
    const int idx = r * 512 + t;
    unsigned long long bal = __ballot(mask[b * LL + idx] > 0);
    if (lane == 0) {
      const int base = (r * 512 + w * 64) >> 5;
      kvb[base] = (unsigned int)bal;
      kvb[base + 1] = (unsigned int)(bal >> 32);
    }
  }
  __syncthreads();

  // ---- phase 1: scores via transposed MFMA (A=K frags, B=Q frags).
  // Wave w handles key-tiles kt = 8j + w; KF loads fully coalesced.
  const unsigned short* qp = Qb + ((size_t)(b * LL + q0 + lc)) * PP + h * HDD;
  const bf16x8 qb0 = ldb8(qp + quad * 8);
  const bf16x8 qb1 = ldb8(qp + 32 + quad * 8);
  float sc[12][4];
  const unsigned short* kfb =
      KF + (((size_t)(b * HH + h) * 96 + w) * 2) * 512 + lane * 8;
#pragma unroll
  for (int j = 0; j < 12; ++j) {
    bf16x8 ka0 = ldb8(kfb + j * 8192);
    bf16x8 ka1 = ldb8(kfb + j * 8192 + 512);
    f32x4 acc = {0.f, 0.f, 0.f, 0.f};
    acc = __builtin_amdgcn_mfma_f32_16x16x32_bf16(ka0, qb0, acc, 0, 0, 0);
    acc = __builtin_amdgcn_mfma_f32_16x16x32_bf16(ka1, qb1, acc, 0, 0, 0);
    sc[j][0] = acc[0];
    sc[j][1] = acc[1];
    sc[j][2] = acc[2];
    sc[j][3] = acc[3];
  }

  // ---- phase 2: masked softmax WITHOUT max pass (scores bounded ~|3|;
  // softmax is shift-invariant so this matches the reference numerically).
  const int kbase = w * 16 + quad * 4;  // key low bits; key = 128j + kbase + r
  const int gamma = kbase >> 5;
  const int beta = kbase & 31;
  float s = 0.f;
#pragma unroll
  for (int j = 0; j < 12; ++j) {
    const unsigned int w4 = (kvb[j * 4 + gamma] >> beta) & 0xFu;
#pragma unroll
    for (int r = 0; r < 4; ++r) {
      float e = ((w4 >> r) & 1u) ? __expf(sc[j][r]) : 0.f;
      sc[j][r] = e;
      s += e;
    }
  }
  s += __shfl_xor(s, 16, 64);
  s += __shfl_xor(s, 32, 64);
  if (lane < 16) red_s[w][lane] = s;
  __syncthreads();
  float tot = 0.f;
#pragma unroll
  for (int ww = 0; ww < 8; ++ww) tot += red_s[ww][lc];
  const float inv = 1.f / tot;
#pragma unroll
  for (int j = 0; j < 12; ++j) {
    uint2 u;
    u.x = (unsigned int)f2b(sc[j][0] * inv) |
          ((unsigned int)f2b(sc[j][1] * inv) << 16);
    u.y = (unsigned int)f2b(sc[j][2] * inv) |
          ((unsigned int)f2b(sc[j][3] * inv) << 16);
    *(uint2*)&p_b[lc][j * 128 + kbase] = u;
  }
  __syncthreads();

  // ---- phase 3: 3 diffusion steps, register-resident, f32x2 packed.
  // Wave w owns rows 2w..2w+1; lane owns keys [lane*24, lane*24+24) as 12
  // pairs. 5-tap conv: even taps (0,2,4) are pair-aligned; odd taps (1,3) are
  // built from existing register halves.
  float wr[5];
  {
    float k0 = kernel_w[0], k1 = kernel_w[1], k2 = kernel_w[2],
          k3 = kernel_w[3], k4 = kernel_w[4];
    float km = fmaxf(fmaxf(fmaxf(k0, k1), fmaxf(k2, k3)), k4);
    float e0 = __expf(k0 - km), e1 = __expf(k1 - km), e2 = __expf(k2 - km),
          e3 = __expf(k3 - km), e4 = __expf(k4 - km);
    float es = e0 + e1 + e2 + e3 + e4;
    wr[0] = e4 / es;
    wr[1] = e3 / es;
    wr[2] = e2 / es;
    wr[3] = e1 / es;
    wr[4] = e0 / es;
  }
  unsigned int db;
  {
    const int w0i = (lane * 24) >> 5, sh = (lane * 24) & 31;
    unsigned long long kw2 =
        ((unsigned long long)kvb[w0i + 1] << 32) | (unsigned long long)kvb[w0i];
    db = (unsigned int)((kw2 >> sh) & 0xFFFFFFu);
  }
  f32x2 fm2[12];
#pragma unroll
  for (int i = 0; i < 12; ++i)
    fm2[i] = mk2((float)((db >> (2 * i)) & 1u), (float)((db >> (2 * i + 1)) & 1u));

  for (int rr = 0; rr < 2; ++rr) {
    const int row = w * 2 + rr;
    f32x2 pg[12];
#pragma unroll
    for (int c = 0; c < 3; ++c) {
      uint4 v = *(const uint4*)&p_b[row][lane * 24 + c * 8];
      unsigned int ws4[4] = {v.x, v.y, v.z, v.w};
#pragma unroll
      for (int q = 0; q < 4; ++q)
        pg[c * 4 + q] =
            mk2(__builtin_bit_cast(float, ws4[q] << 16),
                __builtin_bit_cast(float, ws4[q] & 0xFFFF0000u));
    }
#pragma unroll
    for (int step = 0; step < 3; ++step) {
      float h1 = __shfl_up(pg[11].y, 1);
      float h2 = __shfl_up(pg[11].x, 1);
      float h3 = __shfl_up(pg[10].y, 1);
      float h4 = __shfl_up(pg[10].x, 1);
      if (lane == 0) h1 = h2 = h3 = h4 = 0.f;
      f32x2 ps2[12];
      ps2[0] = wr[0] * pg[0] + wr[1] * mk2(h1, pg[0].x) + wr[2] * mk2(h2, h1) +
               wr[3] * mk2(h3, h2) + wr[4] * mk2(h4, h3);
      ps2[1] = wr[0] * pg[1] + wr[1] * mk2(pg[0].y, pg[1].x) + wr[2] * pg[0] +
               wr[3] * mk2(h1, pg[0].x) + wr[4] * mk2(h2, h1);
#pragma unroll
      for (int i = 2; i < 12; ++i)
        ps2[i] = wr[0] * pg[i] + wr[1] * mk2(pg[i - 1].y, pg[i].x) +
                 wr[2] * pg[i - 1] + wr[3] * mk2(pg[i - 2].y, pg[i - 1].x) +
                 wr[4] * pg[i - 2];
      f32x2 acc2 = mk2(0.f, 0.f);
#pragma unroll
      for (int i = 0; i < 12; ++i) {
        ps2[i] *= fm2[i];
        acc2 += ps2[i];
      }
      float sv = acc2.x + acc2.y;
#pragma unroll
      for (int off = 1; off < 64; off <<= 1) sv += __shfl_xor(sv, off, 64);
      const float pinv = 0.02f / (sv + 1e-9f);
#pragma unroll
      for (int i = 0; i < 12; ++i) pg[i] = 0.98f * pg[i] + ps2[i] * pinv;
    }
#pragma unroll
    for (int c = 0; c < 3; ++c) {
      unsigned int uw[4];
#pragma unroll
      for (int q = 0; q < 4; ++q)
        uw[q] = (unsigned int)f2b(pg[c * 4 + q].x) |
                ((unsigned int)f2b(pg[c * 4 + q].y) << 16);
      uint4 u;
      u.x = uw[0];
      u.y = uw[1];
      u.z = uw[2];
      u.w = uw[3];
      *(uint4*)&p_b[row][lane * 24 + c * 8] = u;
    }
  }
  __syncthreads();

  // ---- phase 4: PV via MFMA, V frags coalesced from fragment-linear VF.
  // Wave pair (w, w+4) owns hd cols (w&3)*16+lc; splits 24 key-chunks 12/12,
  // partials combined through (dead) p_b space.
  const int cidx = (w & 3) * 16 + lc;
  const int gbase = (w >> 2) * 12;
  const unsigned short* vfb =
      VF + ((((size_t)(b * HH + h) * 4 + (w & 3)) * 48 + (w >> 2) * 24) * 512) +
      lane * 8;
  f32x4 oacc = {0.f, 0.f, 0.f, 0.f};
#pragma unroll
  for (int g = 0; g < 12; ++g) {
    const int gg = gbase + g;
#pragma unroll
    for (int c = 0; c < 2; ++c) {
      bf16x8 pa = ldb8(&p_b[lc][gg * 64 + c * 32 + quad * 8]);
      bf16x8 vf = ldb8(vfb + (g * 2 + c) * 512);
      oacc = __builtin_amdgcn_mfma_f32_16x16x32_bf16(pa, vf, oacc, 0, 0, 0);
    }
  }
  __syncthreads();  // all p_b reads done; p_b reusable as fp32 scratch
  float* pscr = (float*)&p_b[0][0];
  if (w >= 4) {
    const int idx = ((((w - 4) * 4 + quad) * 16) + lc) * 4;
    *(float4*)(pscr + idx) =
        make_float4(oacc[0], oacc[1], oacc[2], oacc[3]);
  }
  __syncthreads();
  if (w < 4) {
    const int idx = (((w * 4 + quad) * 16) + lc) * 4;
    float4 pr = *(const float4*)(pscr + idx);
    float o[4] = {oacc[0] + pr.x, oacc[1] + pr.y, oacc[2] + pr.z,
                  oacc[3] + pr.w};
#pragma unroll
    for (int r = 0; r < 4; ++r)
      ctxb[((size_t)(b * LL + q0 + quad * 4 + r)) * PP + h * HDD + cidx] =
          f2b(o[r]);
  }
}

extern "C" void kernel_launch(void* const* d_in, const int* in_sizes, int n_in,
                              void* d_out, int out_size, void* d_ws,
                              size_t ws_size, hipStream_t stream) {
  const float* hs = (const float*)d_in[0];
  const int* mask = (const int*)d_in[1];
  const float* Wq = (const float*)d_in[2];
  const float* bq = (const float*)d_in[3];
  const float* Wk = (const float*)d_in[4];
  const float* bk = (const float*)d_in[5];
  const float* Wv = (const float*)d_in[6];
  const float* bv = (const float*)d_in[7];
  const float* Wo = (const float*)d_in[8];
  const float* bo = (const float*)d_in[9];
  const float* kw = (const float*)d_in[10];

  const size_t NBLP = (size_t)BB * LL * PP;  // 3,145,728 elems
  unsigned short* Qb = (unsigned short*)d_ws;
  unsigned short* KF = Qb + NBLP;   // K fragment-linear
  unsigned short* VF = KF + NBLP;   // V fragment-linear
  unsigned short* ctxb = VF + NBLP; // bf16 ctx
  unsigned short* hsb = ctxb + NBLP;
  unsigned short* WT = hsb + NBLP;  // 4 x [1024][1024] bf16 (n-major)

  dim3 blk(256);
  cast_hs<<<dim3(1536), blk, 0, stream>>>(hs, hsb);
  transpose_w<<<dim3(16, 16, 4), blk, 0, stream>>>(Wq, Wk, Wv, Wo, WT);
  qkv_gemm<<<dim3(8, 48, 3), blk, 0, stream>>>(hsb, WT, bq, bk, bv, Qb, KF, VF);
  attn_kernel<<<dim3(96, 16, 2), dim3(512), 0, stream>>>(Qb, KF, VF, mask, kw,
                                                         ctxb);
  out_gemm<<<dim3(8, 48, 1), blk, 0, stream>>>(ctxb, WT + 3 * 1024 * 1024, bo,
                                               (float*)d_out);
}

// Round 8
// 242.628 us; speedup vs baseline: 1.0348x; 1.0348x over previous
//
#include <hip/hip_runtime.h>

#define BB 2
#define LL 1536
#define DD 1024
#define HH 16
#define HDD 64
#define PP 1024
#define PBS 1544  // p_b row stride in shorts: 16B-aligned

typedef __attribute__((ext_vector_type(8))) __bf16 bf16x8;
typedef __attribute__((ext_vector_type(4))) float f32x4;
typedef __attribute__((ext_vector_type(2))) float f32x2;

__device__ __forceinline__ float b2f(unsigned short u) {
  unsigned int x = ((unsigned int)u) << 16;
  return __builtin_bit_cast(float, x);
}
__device__ __forceinline__ unsigned short f2b(float f) {
  unsigned int x = __builtin_bit_cast(unsigned int, f);
  unsigned int r = (x + 0x7FFFu + ((x >> 16) & 1u)) >> 16;
  return (unsigned short)r;
}
__device__ __forceinline__ bf16x8 ldb8(const unsigned short* p) {
  return __builtin_bit_cast(bf16x8, *(const uint4*)p);
}
__device__ __forceinline__ f32x2 mk2(float a, float b) {
  f32x2 r;
  r.x = a;
  r.y = b;
  return r;
}
// async global->LDS, 16B per lane; lds dst = wave-uniform base + lane*16
__device__ __forceinline__ void gl_lds16(const unsigned short* g,
                                         unsigned short* l) {
  __builtin_amdgcn_global_load_lds(
      (const __attribute__((address_space(1))) void*)g,
      (__attribute__((address_space(3))) void*)l, 16, 0, 0);
}

// ---- DPP wave64 sum reduce: VALU-rate, ~50cyc chain (vs ~240 for ds_bpermute
// butterfly). row_shr 1/2/4/8 -> per-16 row sums in lane15/31/47/63;
// row_bcast15 -> lane31=s0..31, lane63=s32..63; row_bcast31 -> lane63=total.
template <int CTRL>
__device__ __forceinline__ float dppadd(float x) {
  int s = __builtin_amdgcn_update_dpp(0, __builtin_bit_cast(int, x), CTRL, 0xf,
                                      0xf, true);
  return x + __builtin_bit_cast(float, s);
}
__device__ __forceinline__ float wave_sum64(float x) {
  x = dppadd<0x111>(x);  // row_shr:1
  x = dppadd<0x112>(x);  // row_shr:2
  x = dppadd<0x114>(x);  // row_shr:4
  x = dppadd<0x118>(x);  // row_shr:8
  x = dppadd<0x142>(x);  // row_bcast15
  x = dppadd<0x143>(x);  // row_bcast31
  return __builtin_bit_cast(
      float, __builtin_amdgcn_readlane(__builtin_bit_cast(int, x), 63));
}

// ---------------- prep: cast hs -> bf16 AND transpose 4x W -> WT bf16 -------
__global__ __launch_bounds__(256) void prep(
    const float* __restrict__ hs, unsigned short* __restrict__ hsb,
    const float* __restrict__ Wq, const float* __restrict__ Wk,
    const float* __restrict__ Wv, const float* __restrict__ Wo,
    unsigned short* __restrict__ WT) {
  const int bid = blockIdx.x;
  const int t = threadIdx.x;
  if (bid < 1536) {
    const int idx = bid * 2048 + t * 8;
    float4 a = *(const float4*)(hs + idx);
    float4 b = *(const float4*)(hs + idx + 4);
    uint4 u;
    u.x = (unsigned int)f2b(a.x) | ((unsigned int)f2b(a.y) << 16);
    u.y = (unsigned int)f2b(a.z) | ((unsigned int)f2b(a.w) << 16);
    u.z = (unsigned int)f2b(b.x) | ((unsigned int)f2b(b.y) << 16);
    u.w = (unsigned int)f2b(b.z) | ((unsigned int)f2b(b.w) << 16);
    *(uint4*)(hsb + idx) = u;
  } else {
    __shared__ float tile[64][68];
    const int t2 = bid - 1536;
    const int z = t2 >> 8;
    const int bx = t2 & 15, by = (t2 >> 4) & 15;
    const float* W = (z == 0) ? Wq : (z == 1) ? Wk : (z == 2) ? Wv : Wo;
    unsigned short* O = WT + (size_t)z * 1024 * 1024;
    const int r0 = by * 64;  // k rows
    const int c0 = bx * 64;  // n cols
#pragma unroll
    for (int i = 0; i < 4; ++i) {
      const int row = (t >> 4) + i * 16;
      const int col = (t & 15) * 4;
      *(float4*)&tile[row][col] =
          *(const float4*)&W[(size_t)(r0 + row) * 1024 + c0 + col];
    }
    __syncthreads();
#pragma unroll
    for (int i = 0; i < 4; ++i) {
      const int n = (t >> 4) + i * 16;
      const int k4 = (t & 15) * 4;
      uint2 u;
      u.x = (unsigned int)f2b(tile[k4 + 0][n]) |
            ((unsigned int)f2b(tile[k4 + 1][n]) << 16);
      u.y = (unsigned int)f2b(tile[k4 + 2][n]) |
            ((unsigned int)f2b(tile[k4 + 3][n]) << 16);
      *(uint2*)&O[(size_t)(c0 + n) * 1024 + r0 + k4] = u;
    }
  }
}

// ---------------- bf16 MFMA GEMM: C[M,1024] = A[M,1024] @ Bt[1024,1024]^T ----
// 128x128 tile, BK=32, 4 waves, 4x4 MFMA/wave (R6 body — R7's 64x128 regressed).
// MODE 0: Q fragment-linear *0.125. MODE 1: K fragment-linear. MODE 2: V
// fragment-linear. MODE 3: fp32 row-major.
template <int MODE>
__device__ __forceinline__ void gemm_mfma_body(
    const unsigned short* __restrict__ A, const unsigned short* __restrict__ Bt,
    const float* __restrict__ bias, void* __restrict__ Cout) {
  __shared__ unsigned short As[128 * 32];
  __shared__ unsigned short Bs[128 * 32];
  const int t = threadIdx.x;
  const int lane = t & 63;
  const int w = t >> 6;
  const int quad = lane >> 4;
  const int lc = lane & 15;
  const int m0 = blockIdx.y * 128, n0 = blockIdx.x * 128;

  const int sr = lane >> 2;        // row within 16-row group
  const int sk = (lane & 3) * 8;   // k element offset
  const unsigned short* ga0 = A + (size_t)(m0 + w * 32 + sr) * 1024 + sk;
  const unsigned short* ga1 = ga0 + 16 * 1024;
  const unsigned short* gb0 = Bt + (size_t)(n0 + w * 32 + sr) * 1024 + sk;
  const unsigned short* gb1 = gb0 + 16 * 1024;
  unsigned short* la0 = As + w * 1024;
  unsigned short* la1 = As + w * 1024 + 512;
  unsigned short* lb0 = Bs + w * 1024;
  unsigned short* lb1 = Bs + w * 1024 + 512;

  const int mrow0 = (w >> 1) * 64, ncol0 = (w & 1) * 64;

  f32x4 acc[4][4];
#pragma unroll
  for (int i = 0; i < 4; ++i)
#pragma unroll
    for (int j = 0; j < 4; ++j) acc[i][j] = (f32x4){0.f, 0.f, 0.f, 0.f};

  for (int k0 = 0; k0 < 1024; k0 += 32) {
    __syncthreads();  // previous iter's ds_reads done before overwrite
    gl_lds16(ga0 + k0, la0);
    gl_lds16(ga1 + k0, la1);
    gl_lds16(gb0 + k0, lb0);
    gl_lds16(gb1 + k0, lb1);
    __syncthreads();  // staged data visible
    bf16x8 af[4], bfr[4];
#pragma unroll
    for (int i = 0; i < 4; ++i)
      af[i] = ldb8(&As[(mrow0 + i * 16 + lc) * 32 + quad * 8]);
#pragma unroll
    for (int j = 0; j < 4; ++j)
      bfr[j] = ldb8(&Bs[(ncol0 + j * 16 + lc) * 32 + quad * 8]);
#pragma unroll
    for (int i = 0; i < 4; ++i)
#pragma unroll
      for (int j = 0; j < 4; ++j)
        acc[i][j] =
            __builtin_amdgcn_mfma_f32_16x16x32_bf16(af[i], bfr[j], acc[i][j], 0, 0, 0);
  }

#pragma unroll
  for (int i = 0; i < 4; ++i) {
    const int row0 = m0 + mrow0 + i * 16 + quad * 4;  // rows row0..row0+3
#pragma unroll
    for (int jj = 0; jj < 4; ++jj) {
      const int col = n0 + ncol0 + jj * 16 + lc;
      const float bz = bias[col];
      float o[4];
#pragma unroll
      for (int r = 0; r < 4; ++r) o[r] = acc[i][jj][r] + bz;
      if constexpr (MODE == 0) {
        // Q fragment-linear: QF[(bh*96+qt)*2+f][qk*16+m][8], scale 0.125
        const int bb = row0 / LL;
        const int ql = row0 - bb * LL;  // q local; %16 == quad*4
        const int qt = ql >> 4;
        const int m = ql & 15;
        const int hh = col >> 6;
        const int hd = col & 63;
        const int f = hd >> 5;
        const int qk = (hd >> 3) & 3;
        const int j = hd & 7;
        unsigned short* QF = (unsigned short*)Cout;
        const size_t base =
            (((size_t)(bb * HH + hh) * 96 + qt) * 2 + f) * 512 +
            (qk * 16 + m) * 8 + j;
#pragma unroll
        for (int r = 0; r < 4; ++r) QF[base + r * 8] = f2b(o[r] * 0.125f);
      } else if constexpr (MODE == 1) {
        // K fragment-linear: key=row, tile=key/16, m=key%16, col-> f,qk,j
        const int bb = row0 / LL;
        const int kl = row0 - bb * LL;  // key local, %16 == quad*4
        const int ktl = kl >> 4;
        const int m = kl & 15;
        const int hh = col >> 6;
        const int hd = col & 63;
        const int f = hd >> 5;
        const int qk = (hd >> 3) & 3;
        const int j = hd & 7;
        unsigned short* KF = (unsigned short*)Cout;
        const size_t base =
            (((size_t)(bb * HH + hh) * 96 + ktl) * 2 + f) * 512 +
            (qk * 16 + m) * 8 + j;
#pragma unroll
        for (int r = 0; r < 4; ++r) KF[base + r * 8] = f2b(o[r]);
      } else if constexpr (MODE == 2) {
        // V fragment-linear: r=0..3 -> 4 consecutive j -> one uint2 store
        const int bb = row0 / LL;
        const int kl = row0 - bb * LL;  // key local of r=0
        const int hh = col >> 6;
        const int hd = col & 63;
        const int hg = hd >> 4;
        const int lcv = hd & 15;
        const int tile = (kl >> 5);        // gg*2 + c
        const int qv = (kl >> 3) & 3;
        const int j0 = kl & 7;             // 0 or 4
        unsigned short* VF = (unsigned short*)Cout;
        const size_t base =
            (((size_t)(bb * HH + hh) * 4 + hg) * 48 + tile) * 512 +
            (qv * 16 + lcv) * 8 + j0;
        uint2 u;
        u.x = (unsigned int)f2b(o[0]) | ((unsigned int)f2b(o[1]) << 16);
        u.y = (unsigned int)f2b(o[2]) | ((unsigned int)f2b(o[3]) << 16);
        *(uint2*)&VF[base] = u;
      } else {
#pragma unroll
        for (int r = 0; r < 4; ++r)
          ((float*)Cout)[(size_t)(row0 + r) * 1024 + col] = o[r];
      }
    }
  }
}

__global__ __launch_bounds__(256) void qkv_gemm(
    const unsigned short* __restrict__ hsb, const unsigned short* __restrict__ WT,
    const float* __restrict__ bq, const float* __restrict__ bk,
    const float* __restrict__ bv, unsigned short* __restrict__ QF,
    unsigned short* __restrict__ KF, unsigned short* __restrict__ VF) {
  if (blockIdx.z == 0) {
    gemm_mfma_body<0>(hsb, WT, bq, QF);
  } else if (blockIdx.z == 1) {
    gemm_mfma_body<1>(hsb, WT + 1024 * 1024, bk, KF);
  } else {
    gemm_mfma_body<2>(hsb, WT + 2 * 1024 * 1024, bv, VF);
  }
}

__global__ __launch_bounds__(256) void out_gemm(
    const unsigned short* __restrict__ ctxb,
    const unsigned short* __restrict__ WoT, const float* __restrict__ bo,
    float* __restrict__ out) {
  gemm_mfma_body<3>(ctxb, WoT, bo, out);
}

// ---------------- fused attention: scores -> softmax -> 3x diffusion -> PV ----
// One block per (b, h, 16-row q tile), 512 threads / 8 waves.
// R8: Q fragment-linear (coalesced), DPP wave-sum in diffusion (kills the
// 6-deep ds_bpermute latency chain).
__global__ __launch_bounds__(512, 4) void attn_kernel(
    const unsigned short* __restrict__ QF, const unsigned short* __restrict__ KF,
    const unsigned short* __restrict__ VF, const int* __restrict__ mask,
    const float* __restrict__ kernel_w, unsigned short* __restrict__ ctxb) {
  __shared__ __align__(16) unsigned short p_b[16][PBS];  // ~48.2 KB
  __shared__ unsigned int kvb[50];                       // packed key-valid bits
  __shared__ float red_s[8][16];

  const int t = threadIdx.x;
  const int lane = t & 63;
  const int w = t >> 6;        // wave id 0..7
  const int quad = lane >> 4;  // 0..3
  const int lc = lane & 15;
  const int b = blockIdx.z, h = blockIdx.y;
  const int q0 = blockIdx.x * 16;

  // key-valid bitmask via per-wave ballot (keys r*512 + w*64 + lane)
  if (t < 2) kvb[48 + t] = 0;
#pragma unroll
  for (int r = 0; r < 3; ++r) {
    const int idx = r * 512 + t;
    unsigned long long bal = __ballot(mask[b * LL + idx] > 0);
    if (lane == 0) {
      const int base = (r * 512 + w * 64) >> 5;
      kvb[base] = (unsigned int)bal;
      kvb[base + 1] = (unsigned int)(bal >> 32);
    }
  }
  __syncthreads();

  // ---- phase 1: scores via transposed MFMA (A=K frags, B=Q frags).
  // Wave w handles key-tiles kt = 8j + w; all frag loads fully coalesced.
  const unsigned short* qfb =
      QF + (((size_t)(b * HH + h) * 96 + (q0 >> 4)) * 2) * 512 + lane * 8;
  const bf16x8 qb0 = ldb8(qfb);
  const bf16x8 qb1 = ldb8(qfb + 512);
  float sc[12][4];
  const unsigned short* kfb =
      KF + (((size_t)(b * HH + h) * 96 + w) * 2) * 512 + lane * 8;
#pragma unroll
  for (int j = 0; j < 12; ++j) {
    bf16x8 ka0 = ldb8(kfb + j * 8192);
    bf16x8 ka1 = ldb8(kfb + j * 8192 + 512);
    f32x4 acc = {0.f, 0.f, 0.f, 0.f};
    acc = __builtin_amdgcn_mfma_f32_16x16x32_bf16(ka0, qb0, acc, 0, 0, 0);
    acc = __builtin_amdgcn_mfma_f32_16x16x32_bf16(ka1, qb1, acc, 0, 0, 0);
    sc[j][0] = acc[0];
    sc[j][1] = acc[1];
    sc[j][2] = acc[2];
    sc[j][3] = acc[3];
  }

  // ---- phase 2: masked softmax WITHOUT max pass (scores bounded ~|3|;
  // softmax is shift-invariant so this matches the reference numerically).
  const int kbase = w * 16 + quad * 4;  // key low bits; key = 128j + kbase + r
  const int gamma = kbase >> 5;
  const int beta = kbase & 31;
  float s = 0.f;
#pragma unroll
  for (int j = 0; j < 12; ++j) {
    const unsigned int w4 = (kvb[j * 4 + gamma] >> beta) & 0xFu;
#pragma unroll
    for (int r = 0; r < 4; ++r) {
      float e = ((w4 >> r) & 1u) ? __expf(sc[j][r]) : 0.f;
      sc[j][r] = e;
      s += e;
    }
  }
  s += __shfl_xor(s, 16, 64);
  s += __shfl_xor(s, 32, 64);
  if (lane < 16) red_s[w][lane] = s;
  __syncthreads();
  float tot0 = 0.f;
#pragma unroll
  for (int ww = 0; ww < 8; ++ww) tot0 += red_s[ww][lc];
  const float inv = 1.f / tot0;
#pragma unroll
  for (int j = 0; j < 12; ++j) {
    uint2 u;
    u.x = (unsigned int)f2b(sc[j][0] * inv) |
          ((unsigned int)f2b(sc[j][1] * inv) << 16);
    u.y = (unsigned int)f2b(sc[j][2] * inv) |
          ((unsigned int)f2b(sc[j][3] * inv) << 16);
    *(uint2*)&p_b[lc][j * 128 + kbase] = u;
  }
  __syncthreads();

  // ---- phase 3: 3 diffusion steps, register-resident, f32x2 packed.
  // Wave w owns rows 2w..2w+1; lane owns keys [lane*24, lane*24+24) as 12
  // pairs. Per-step sum via DPP wave reduce (VALU-rate).
  float wr[5];
  {
    float k0 = kernel_w[0], k1 = kernel_w[1], k2 = kernel_w[2],
          k3 = kernel_w[3], k4 = kernel_w[4];
    float km = fmaxf(fmaxf(fmaxf(k0, k1), fmaxf(k2, k3)), k4);
    float e0 = __expf(k0 - km), e1 = __expf(k1 - km), e2 = __expf(k2 - km),
          e3 = __expf(k3 - km), e4 = __expf(k4 - km);
    float es = e0 + e1 + e2 + e3 + e4;
    wr[0] = e4 / es;
    wr[1] = e3 / es;
    wr[2] = e2 / es;
    wr[3] = e1 / es;
    wr[4] = e0 / es;
  }
  unsigned int db;
  {
    const int w0i = (lane * 24) >> 5, sh = (lane * 24) & 31;
    unsigned long long kw2 =
        ((unsigned long long)kvb[w0i + 1] << 32) | (unsigned long long)kvb[w0i];
    db = (unsigned int)((kw2 >> sh) & 0xFFFFFFu);
  }
  f32x2 fm2[12];
#pragma unroll
  for (int i = 0; i < 12; ++i)
    fm2[i] = mk2((float)((db >> (2 * i)) & 1u), (float)((db >> (2 * i + 1)) & 1u));

  for (int rr = 0; rr < 2; ++rr) {
    const int row = w * 2 + rr;
    f32x2 pg[12];
#pragma unroll
    for (int c = 0; c < 3; ++c) {
      uint4 v = *(const uint4*)&p_b[row][lane * 24 + c * 8];
      unsigned int ws4[4] = {v.x, v.y, v.z, v.w};
#pragma unroll
      for (int q = 0; q < 4; ++q)
        pg[c * 4 + q] =
            mk2(__builtin_bit_cast(float, ws4[q] << 16),
                __builtin_bit_cast(float, ws4[q] & 0xFFFF0000u));
    }
#pragma unroll
    for (int step = 0; step < 3; ++step) {
      float h1 = __shfl_up(pg[11].y, 1);
      float h2 = __shfl_up(pg[11].x, 1);
      float h3 = __shfl_up(pg[10].y, 1);
      float h4 = __shfl_up(pg[10].x, 1);
      if (lane == 0) h1 = h2 = h3 = h4 = 0.f;
      f32x2 ps2[12];
      ps2[0] = wr[0] * pg[0] + wr[1] * mk2(h1, pg[0].x) + wr[2] * mk2(h2, h1) +
               wr[3] * mk2(h3, h2) + wr[4] * mk2(h4, h3);
      ps2[1] = wr[0] * pg[1] + wr[1] * mk2(pg[0].y, pg[1].x) + wr[2] * pg[0] +
               wr[3] * mk2(h1, pg[0].x) + wr[4] * mk2(h2, h1);
#pragma unroll
      for (int i = 2; i < 12; ++i)
        ps2[i] = wr[0] * pg[i] + wr[1] * mk2(pg[i - 1].y, pg[i].x) +
                 wr[2] * pg[i - 1] + wr[3] * mk2(pg[i - 2].y, pg[i - 1].x) +
                 wr[4] * pg[i - 2];
      f32x2 acc2 = mk2(0.f, 0.f);
#pragma unroll
      for (int i = 0; i < 12; ++i) {
        ps2[i] *= fm2[i];
        acc2 += ps2[i];
      }
      const float tot = wave_sum64(acc2.x + acc2.y);
      const float pinv = 0.02f / (tot + 1e-9f);
#pragma unroll
      for (int i = 0; i < 12; ++i) pg[i] = 0.98f * pg[i] + ps2[i] * pinv;
    }
#pragma unroll
    for (int c = 0; c < 3; ++c) {
      unsigned int uw[4];
#pragma unroll
      for (int q = 0; q < 4; ++q)
        uw[q] = (unsigned int)f2b(pg[c * 4 + q].x) |
                ((unsigned int)f2b(pg[c * 4 + q].y) << 16);
      uint4 u;
      u.x = uw[0];
      u.y = uw[1];
      u.z = uw[2];
      u.w = uw[3];
      *(uint4*)&p_b[row][lane * 24 + c * 8] = u;
    }
  }
  __syncthreads();

  // ---- phase 4: PV via MFMA, V frags coalesced from fragment-linear VF.
  // Wave pair (w, w+4) owns hd cols (w&3)*16+lc; splits 24 key-chunks 12/12,
  // partials combined through (dead) p_b space.
  const int cidx = (w & 3) * 16 + lc;
  const int gbase = (w >> 2) * 12;
  const unsigned short* vfb =
      VF + ((((size_t)(b * HH + h) * 4 + (w & 3)) * 48 + (w >> 2) * 24) * 512) +
      lane * 8;
  f32x4 oacc = {0.f, 0.f, 0.f, 0.f};
#pragma unroll
  for (int g = 0; g < 12; ++g) {
    const int gg = gbase + g;
#pragma unroll
    for (int c = 0; c < 2; ++c) {
      bf16x8 pa = ldb8(&p_b[lc][gg * 64 + c * 32 + quad * 8]);
      bf16x8 vf = ldb8(vfb + (g * 2 + c) * 512);
      oacc = __builtin_amdgcn_mfma_f32_16x16x32_bf16(pa, vf, oacc, 0, 0, 0);
    }
  }
  __syncthreads();  // all p_b reads done; p_b reusable as fp32 scratch
  float* pscr = (float*)&p_b[0][0];
  if (w >= 4) {
    const int idx = ((((w - 4) * 4 + quad) * 16) + lc) * 4;
    *(float4*)(pscr + idx) =
        make_float4(oacc[0], oacc[1], oacc[2], oacc[3]);
  }
  __syncthreads();
  if (w < 4) {
    const int idx = (((w * 4 + quad) * 16) + lc) * 4;
    float4 pr = *(const float4*)(pscr + idx);
    float o[4] = {oacc[0] + pr.x, oacc[1] + pr.y, oacc[2] + pr.z,
                  oacc[3] + pr.w};
#pragma unroll
    for (int r = 0; r < 4; ++r)
      ctxb[((size_t)(b * LL + q0 + quad * 4 + r)) * PP + h * HDD + cidx] =
          f2b(o[r]);
  }
}

extern "C" void kernel_launch(void* const* d_in, const int* in_sizes, int n_in,
                              void* d_out, int out_size, void* d_ws,
                              size_t ws_size, hipStream_t stream) {
  const float* hs = (const float*)d_in[0];
  const int* mask = (const int*)d_in[1];
  const float* Wq = (const float*)d_in[2];
  const float* bq = (const float*)d_in[3];
  const float* Wk = (const float*)d_in[4];
  const float* bk = (const float*)d_in[5];
  const float* Wv = (const float*)d_in[6];
  const float* bv = (const float*)d_in[7];
  const float* Wo = (const float*)d_in[8];
  const float* bo = (const float*)d_in[9];
  const float* kw = (const float*)d_in[10];

  const size_t NBLP = (size_t)BB * LL * PP;  // 3,145,728 elems
  unsigned short* QF = (unsigned short*)d_ws;  // Q fragment-linear
  unsigned short* KF = QF + NBLP;   // K fragment-linear
  unsigned short* VF = KF + NBLP;   // V fragment-linear
  unsigned short* ctxb = VF + NBLP; // bf16 ctx
  unsigned short* hsb = ctxb + NBLP;
  unsigned short* WT = hsb + NBLP;  // 4 x [1024][1024] bf16 (n-major)

  dim3 blk(256);
  prep<<<dim3(2560), blk, 0, stream>>>(hs, hsb, Wq, Wk, Wv, Wo, WT);
  qkv_gemm<<<dim3(8, 24, 3), blk, 0, stream>>>(hsb, WT, bq, bk, bv, QF, KF, VF);
  attn_kernel<<<dim3(96, 16, 2), dim3(512), 0, stream>>>(QF, KF, VF, mask, kw,
                                                         ctxb);
  out_gemm<<<dim3(8, 24, 1), blk, 0, stream>>>(ctxb, WT + 3 * 1024 * 1024, bo,
                                               (float*)d_out);
}